// Round 5
// baseline (86.475 us; speedup 1.0000x reference)
//
#include <hip/hip_runtime.h>
#include <hip/hip_bf16.h>

// SNNonLocalBlock: B=16, H=W=64, C=256, L=4096, Ld=1024
// Round 5: k_attn restructured 2 waves x 32q -> 4 waves x 16q (256 thr),
// doubling waves/CU (8 -> 16) to attack the latency-bound main loop.
// Staging (global_load_lds, pre-swizzled sources, 2-deep dbuf) unchanged.

typedef __attribute__((ext_vector_type(8))) short bf16x8;
typedef __attribute__((ext_vector_type(4))) short bf16x4;
typedef __attribute__((ext_vector_type(4))) float f32x4;

#define MFMA16(A,B,C) __builtin_amdgcn_mfma_f32_16x16x32_bf16(A,B,C,0,0,0)

#define GLOAD16(GSRC, LDST)                                                        \
    __builtin_amdgcn_global_load_lds(                                              \
        (const __attribute__((address_space(1))) unsigned int*)(GSRC),             \
        (__attribute__((address_space(3))) unsigned int*)(LDST), 16, 0, 0)

static __device__ __forceinline__ unsigned short f2b(float f) {
    __hip_bfloat16 h = __float2bfloat16(f);
    return *reinterpret_cast<unsigned short*>(&h);
}
static __device__ __forceinline__ float blo(unsigned int u){ return __uint_as_float(u << 16); }
static __device__ __forceinline__ float bhi(unsigned int u){ return __uint_as_float(u & 0xffff0000u); }

// ---------------------------------------------------------------------------
// K0: prep: WT[192 n][256 k] bf16 = [w_theta|w_phi|w_g]^T ; woT[256 c][128 d] bf16
// ---------------------------------------------------------------------------
__global__ void k_prep(const float* __restrict__ w_theta, const float* __restrict__ w_phi,
                       const float* __restrict__ w_g, const float* __restrict__ w_o,
                       unsigned short* __restrict__ WT, unsigned short* __restrict__ woT)
{
    int bid = blockIdx.x, t = threadIdx.x;
    if (bid < 192) {
        int n = bid;
        float v;
        if (n < 32)      v = w_theta[t * 32 + n];
        else if (n < 64) v = w_phi[t * 32 + (n - 32)];
        else             v = w_g[t * 128 + (n - 64)];
        WT[n * 256 + t] = f2b(v);
    } else if (t < 128) {
        int cc = bid - 192;
        woT[cc * 128 + t] = f2b(w_o[t * 256 + cc]);
    }
}

// ---------------------------------------------------------------------------
// K1: proj MFMA: out[65536,192] = x @ W. 128-row blocks, BK=64, 4 waves.
// ---------------------------------------------------------------------------
__global__ __launch_bounds__(256) void k_proj(
    const float* __restrict__ x, const unsigned short* __restrict__ WT,
    unsigned short* __restrict__ theta_b, unsigned short* __restrict__ phi_b,
    unsigned short* __restrict__ g_b)
{
    __shared__ unsigned short xT[128 * 64];   // [m][64k] swizzled, 16KB
    __shared__ unsigned short wT[192 * 64];   // [n][64k] swizzled, 24KB
    const int t = threadIdx.x;
    const int w = t >> 6, l = t & 63, G = l >> 4, c = l & 15;
    const size_t row0 = (size_t)blockIdx.x * 128;

    f32x4 acc[2][12];
#pragma unroll
    for (int i = 0; i < 2; i++)
#pragma unroll
        for (int j = 0; j < 12; j++) acc[i][j] = (f32x4){0.f, 0.f, 0.f, 0.f};

    for (int k0 = 0; k0 < 256; k0 += 64) {
        __syncthreads();
#pragma unroll
        for (int it = 0; it < 4; it++) {           // x tile: 128 rows x 8 slots
            int u = it * 256 + t, r = u >> 3, s = u & 7;
            const float* px = x + (row0 + r) * 256 + k0 + s * 8;
            float4 a = *(const float4*)px;
            float4 bq = *(const float4*)(px + 4);
            uint4 v;
            v.x = (unsigned)f2b(a.x) | ((unsigned)f2b(a.y) << 16);
            v.y = (unsigned)f2b(a.z) | ((unsigned)f2b(a.w) << 16);
            v.z = (unsigned)f2b(bq.x) | ((unsigned)f2b(bq.y) << 16);
            v.w = (unsigned)f2b(bq.z) | ((unsigned)f2b(bq.w) << 16);
            *(uint4*)((char*)xT + r * 128 + ((s * 16) ^ ((r & 7) << 4))) = v;
        }
#pragma unroll
        for (int it = 0; it < 6; it++) {           // W tile: 192 rows x 8 slots
            int u = it * 256 + t, r = u >> 3, s = u & 7;
            uint4 v = *(const uint4*)(WT + r * 256 + k0 + s * 8);
            *(uint4*)((char*)wT + r * 128 + ((s * 16) ^ ((r & 7) << 4))) = v;
        }
        __syncthreads();
#pragma unroll
        for (int kin = 0; kin < 2; kin++) {
            int m0r = (2 * w) * 16 + c, m1r = (2 * w + 1) * 16 + c;
            bf16x8 a0 = *(const bf16x8*)((char*)xT + m0r * 128 + ((kin * 64 + G * 16) ^ ((m0r & 7) << 4)));
            bf16x8 a1 = *(const bf16x8*)((char*)xT + m1r * 128 + ((kin * 64 + G * 16) ^ ((m1r & 7) << 4)));
#pragma unroll
            for (int nt = 0; nt < 12; nt++) {
                int nr = nt * 16 + c;
                bf16x8 bv = *(const bf16x8*)((char*)wT + nr * 128 + ((kin * 64 + G * 16) ^ ((nr & 7) << 4)));
                acc[0][nt] = MFMA16(a0, bv, acc[0][nt]);
                acc[1][nt] = MFMA16(a1, bv, acc[1][nt]);
            }
        }
    }
#pragma unroll
    for (int mt = 0; mt < 2; mt++)
#pragma unroll
        for (int nt = 0; nt < 12; nt++)
#pragma unroll
            for (int i = 0; i < 4; i++) {
                size_t row = row0 + (2 * w + mt) * 16 + 4 * G + i;
                unsigned short v = f2b(acc[mt][nt][i]);
                if (nt < 2)      theta_b[row * 32 + nt * 16 + c] = v;
                else if (nt < 4) phi_b[row * 32 + (nt - 2) * 16 + c] = v;
                else             g_b[row * 128 + (nt - 4) * 16 + c] = v;
            }
}

// ---------------------------------------------------------------------------
// K2: pool. blocks [0,1024): phi -> phi_p [b][1024][32] PRE-SWIZZLED
//            (16B blk within 64B row XOR'd by (m&3): u32 idx d2 ^= (m&3)<<2)
//          blocks [1024,1536): g -> pooled + transposed g_pT [b][128 d][1024 m]
//            PRE-SWIZZLED (m idx ^= (d&7)<<3)
// ---------------------------------------------------------------------------
__global__ __launch_bounds__(256) void k_pool(
    const unsigned short* __restrict__ phi_b, const unsigned short* __restrict__ g_b,
    unsigned short* __restrict__ phi_p, unsigned short* __restrict__ g_pT)
{
    const int bid = blockIdx.x, t = threadIdx.x;
    if (bid < 1024) {
        const unsigned int* p32 = (const unsigned int*)phi_b;
        unsigned int* pp32 = (unsigned int*)phi_p;
        int idx = bid * 256 + t;
        int b = idx >> 14, r = idx & 16383, pm = r >> 4, d2 = r & 15;
        int hp = pm >> 5, wp = pm & 31;
        size_t base = ((size_t)b * 4096 + (2 * hp) * 64 + 2 * wp) * 16 + d2;
        unsigned v0 = p32[base], v1 = p32[base + 16], v2 = p32[base + 1024], v3 = p32[base + 1040];
        float lo = fmaxf(fmaxf(blo(v0), blo(v1)), fmaxf(blo(v2), blo(v3)));
        float hi = fmaxf(fmaxf(bhi(v0), bhi(v1)), fmaxf(bhi(v2), bhi(v3)));
        pp32[(idx & ~15) | (d2 ^ ((pm & 3) << 2))] =
            (unsigned)f2b(lo) | ((unsigned)f2b(hi) << 16);
    } else {
        __shared__ unsigned short P[32 * 128];   // [wp][128 d], rows 256B, swz key (wp&7)<<4
        int b = (bid - 1024) >> 5, hp = (bid - 1024) & 31;
        const unsigned int* g32 = (const unsigned int*)g_b;
#pragma unroll
        for (int it = 0; it < 8; it++) {
            int u = it * 256 + t, wp = u >> 6, d2 = u & 63;
            size_t base = ((size_t)b * 4096 + (2 * hp) * 64 + 2 * wp) * 64 + d2;
            unsigned v0 = g32[base], v1 = g32[base + 64], v2 = g32[base + 4096], v3 = g32[base + 4160];
            float lo = fmaxf(fmaxf(blo(v0), blo(v1)), fmaxf(blo(v2), blo(v3)));
            float hi = fmaxf(fmaxf(bhi(v0), bhi(v1)), fmaxf(bhi(v2), bhi(v3)));
            unsigned pv = (unsigned)f2b(lo) | ((unsigned)f2b(hi) << 16);
            *(unsigned*)((char*)P + wp * 256 + ((d2 * 4) ^ ((wp & 7) << 4))) = pv;
        }
        __syncthreads();
#pragma unroll
        for (int it = 0; it < 2; it++) {
            int d = t & 127, s4 = (t >> 7) + it * 2;
            union { unsigned short v[8]; uint4 q; } pk;
#pragma unroll
            for (int k = 0; k < 8; k++) {
                int wp = s4 * 8 + k;
                pk.v[k] = *(const unsigned short*)((char*)P + wp * 256 + ((d * 2) ^ ((wp & 7) << 4)));
            }
            int midx = (hp * 32 + s4 * 8) ^ ((d & 7) << 3);   // pre-swizzle m blocks
            *(uint4*)(g_pT + ((size_t)b * 128 + d) * 1024 + midx) = pk.q;
        }
    }
}

// ---------------------------------------------------------------------------
// K3: fused flash attention. 256 threads (4 waves, 16 q each), 64 q rows/block,
// 16 m-chunks of 64. global_load_lds double-buffer, counted vmcnt(5)/wave.
// ---------------------------------------------------------------------------
__global__ __launch_bounds__(256, 4) void k_attn(
    const unsigned short* __restrict__ theta_b, const unsigned short* __restrict__ phi_p,
    const unsigned short* __restrict__ g_pT, const unsigned short* __restrict__ woT,
    const float* __restrict__ x, const float* __restrict__ b_o,
    const float* __restrict__ sigma_p, float* __restrict__ out)
{
    // buf0 @0 (g 16KB | phi 4KB @16384), buf1 @20480 (g | phi @36864)
    // theta staged in buf1.phi region. Epilogue: O_l @0 (16KB), wo_l @20480 (16KB).
    __shared__ char lds[40960];

    const int t = threadIdx.x;
    const int w = t >> 6, l = t & 63, G = l >> 4, c = l & 15;
    const int bid = (blockIdx.x & 7) * 128 + (blockIdx.x >> 3);   // XCD swizzle (bijective)
    const int b = bid >> 6;
    const int q0 = (bid & 63) * 64;
    const int xr = (c & 7) << 4;       // 128B/256B-row swizzle key
    const int xr3 = (c & 3) << 4;      // 64B-row swizzle key

    const unsigned short* gsrc_base = g_pT + (size_t)b * 131072;
    const unsigned short* psrc_base = phi_p + (size_t)b * 32768;
    // per-wave: 4 g-loads + 1 phi-load per chunk -> counted vmcnt(5)
#define STAGE(BI, MCN)                                                                  \
    {                                                                                   \
        char* gb = lds + (BI) * 20480;                                                  \
        char* pb = gb + 16384;                                                          \
        _Pragma("unroll")                                                               \
        for (int it = 0; it < 4; it++) {                                                \
            int d = 32 * it + 8 * w + (l >> 3), s = l & 7;                              \
            GLOAD16(gsrc_base + (size_t)d * 1024 + (MCN) * 64 + s * 8,                  \
                    gb + it * 4096 + w * 1024);                                         \
        }                                                                               \
        {                                                                               \
            int r = 16 * w + (l >> 2), s = l & 3;                                       \
            GLOAD16(psrc_base + (size_t)((MCN) * 64 + r) * 32 + s * 8,                  \
                    pb + w * 1024);                                                     \
        }                                                                               \
    }

    // prologue: stage chunk 0 + theta (theta in buf1.phi region, 64B rows swz (r&3))
    STAGE(0, 0);
    {
        char* th = lds + 36864;
        int r = t >> 2, s = t & 3;
        uint4 v = *(const uint4*)(theta_b + ((size_t)(b * 4096 + q0 + r)) * 32 + s * 8);
        *(uint4*)(th + r * 64 + ((s * 16) ^ ((r & 3) << 4))) = v;
    }
    __syncthreads();   // drains vmcnt+lgkm: chunk0 + theta in LDS

    // wave w's theta B-frag: rows [16w, 16w+16)
    const bf16x8 bt = *(const bf16x8*)(lds + 36864 + (w * 16 + c) * 64 + ((G * 16) ^ xr3));
    __syncthreads();   // bt reads complete before iter0 stages buf1

    f32x4 oacc[8];
#pragma unroll
    for (int dt = 0; dt < 8; dt++) oacc[dt] = (f32x4){0.f, 0.f, 0.f, 0.f};
    float ps = 0.f;
    const f32x4 zf = (f32x4){0.f, 0.f, 0.f, 0.f};

    for (int mc = 0; mc < 16; mc++) {
        const int cur = mc & 1;
        if (mc < 15) {
            STAGE(cur ^ 1, mc + 1);                        // next chunk in flight
            asm volatile("s_waitcnt vmcnt(5)" ::: "memory");   // cur's 5 landed
        } else {
            asm volatile("s_waitcnt vmcnt(0)" ::: "memory");
        }
        __builtin_amdgcn_sched_barrier(0);
        __builtin_amdgcn_s_barrier();                      // all waves' cur landed
        __builtin_amdgcn_sched_barrier(0);

        const char* gL   = lds + cur * 20480;
        const char* phiL = gL + 16384;

        // S^T = phi @ theta^T : lane (G,c) gets S[m = mt*16+4G+i][q = 16w+c]
        bf16x8 ap[4];
#pragma unroll
        for (int mt = 0; mt < 4; mt++)
            ap[mt] = *(const bf16x8*)(phiL + (mt * 16 + c) * 64 + ((G * 16) ^ xr3));
        f32x4 sacc[4];
        __builtin_amdgcn_s_setprio(1);
#pragma unroll
        for (int mt = 0; mt < 4; mt++) sacc[mt] = MFMA16(ap[mt], bt, zf);
        __builtin_amdgcn_s_setprio(0);

        // exp (no max-sub: |S| << 88) -> packed P A-frags + rowsum partial
        bf16x8 pa[2];
#pragma unroll
        for (int ks = 0; ks < 2; ks++) {
            union { unsigned u[4]; bf16x8 v; } pu;
#pragma unroll
            for (int hf = 0; hf < 2; hf++) {
                int mt = 2 * ks + hf;
                float p0 = __expf(sacc[mt][0]);
                float p1 = __expf(sacc[mt][1]);
                float p2 = __expf(sacc[mt][2]);
                float p3 = __expf(sacc[mt][3]);
                ps += (p0 + p1) + (p2 + p3);
                pu.u[hf * 2]     = (unsigned)f2b(p0) | ((unsigned)f2b(p1) << 16);
                pu.u[hf * 2 + 1] = (unsigned)f2b(p2) | ((unsigned)f2b(p3) << 16);
            }
            pa[ks] = pu.v;
        }

        // O += P @ g
        __builtin_amdgcn_s_setprio(1);
#pragma unroll
        for (int ks = 0; ks < 2; ks++) {
#pragma unroll
            for (int dt = 0; dt < 8; dt++) {
                const char* rb = gL + (dt * 16 + c) * 128;
                bf16x4 x0 = *(const bf16x4*)(rb + ((64 * ks + 8 * G) ^ xr));
                bf16x4 x1 = *(const bf16x4*)(rb + ((64 * ks + 32 + 8 * G) ^ xr));
                bf16x8 bg = __builtin_shufflevector(x0, x1, 0, 1, 2, 3, 4, 5, 6, 7);
                oacc[dt] = MFMA16(pa[ks], bg, oacc[dt]);
            }
        }
        __builtin_amdgcn_s_setprio(0);

        asm volatile("s_waitcnt lgkmcnt(0)" ::: "memory");  // cur reads done
        __builtin_amdgcn_sched_barrier(0);
        __builtin_amdgcn_s_barrier();                       // safe to overwrite cur
        __builtin_amdgcn_sched_barrier(0);
    }
#undef STAGE

    // rowsum: lanes {c, c+16, c+32, c+48} hold partials for q=16w+c
    ps += __shfl_xor(ps, 16);
    ps += __shfl_xor(ps, 32);
    float rinv[4];
#pragma unroll
    for (int i = 0; i < 4; i++) rinv[i] = 1.0f / __shfl(ps, 4 * G + i);

    // normalized O -> O_l [64 q][128 d] bf16 @buf0 (all buf readers finished)
    char* O_l = lds;
#pragma unroll
    for (int dt = 0; dt < 8; dt++)
#pragma unroll
        for (int i = 0; i < 4; i++) {
            int row = w * 16 + 4 * G + i, d = dt * 16 + c;
            *(unsigned short*)(O_l + row * 256 + ((d * 2) ^ ((row & 7) << 4))) =
                f2b(oacc[dt][i] * rinv[i]);
        }

    const float sg = *sigma_p;
    char* wo_l = lds + 20480;
    const int arow = (w * 16 + c) * 256;

    for (int cb = 0; cb < 4; cb++) {
        __syncthreads();                            // O_l visible / prev wo_l reads done
#pragma unroll
        for (int it = 0; it < 4; it++) {            // stage woT quarter [64 c][128 d]
            int u = it * 256 + t, r = u >> 4, s = u & 15;
            uint4 v = *(const uint4*)(woT + (size_t)(cb * 64 + r) * 128 + s * 8);
            *(uint4*)(wo_l + r * 256 + ((s * 16) ^ ((r & 7) << 4))) = v;
        }
        __syncthreads();
        f32x4 eacc[4];
#pragma unroll
        for (int ct = 0; ct < 4; ct++) eacc[ct] = (f32x4){0.f, 0.f, 0.f, 0.f};
#pragma unroll
        for (int ks = 0; ks < 4; ks++) {
            bf16x8 a0 = *(const bf16x8*)(O_l + arow + ((ks * 64 + G * 16) ^ xr));
#pragma unroll
            for (int ct = 0; ct < 4; ct++) {
                bf16x8 bw = *(const bf16x8*)(wo_l + (ct * 16 + c) * 256 + ((ks * 64 + G * 16) ^ xr));
                eacc[ct] = MFMA16(a0, bw, eacc[ct]);
            }
        }
#pragma unroll
        for (int ct = 0; ct < 4; ct++) {
            int col = cb * 64 + ct * 16 + c;
            float bo = b_o[col];
#pragma unroll
            for (int i = 0; i < 4; i++) {
                size_t off = ((size_t)(b * 4096 + q0 + w * 16 + 4 * G + i)) * 256 + col;
                out[off] = x[off] + sg * (eacc[ct][i] + bo);
            }
        }
    }
}

// ---------------------------------------------------------------------------
extern "C" void kernel_launch(void* const* d_in, const int* in_sizes, int n_in,
                              void* d_out, int out_size, void* d_ws, size_t ws_size,
                              hipStream_t stream)
{
    const float* x       = (const float*)d_in[0];
    const float* w_theta = (const float*)d_in[1];
    const float* w_phi   = (const float*)d_in[2];
    const float* w_g     = (const float*)d_in[3];
    const float* w_o     = (const float*)d_in[4];
    const float* b_o     = (const float*)d_in[5];
    const float* sigma   = (const float*)d_in[6];
    float* out = (float*)d_out;

    char* ws = (char*)d_ws;
    unsigned short* theta_b = (unsigned short*)(ws);              //  4 MB [B,4096,32]
    unsigned short* phi_b   = (unsigned short*)(ws + 4194304);    //  4 MB [B,4096,32]
    unsigned short* g_b     = (unsigned short*)(ws + 8388608);    // 16 MB [B,4096,128]
    unsigned short* phi_p   = (unsigned short*)(ws + 25165824);   //  1 MB [B,1024,32] pre-swz
    unsigned short* g_pT    = (unsigned short*)(ws + 26214400);   //  4 MB [B,128,1024] pre-swz
    unsigned short* WT      = (unsigned short*)(ws + 30408704);   // 96 KB [192,256]
    unsigned short* woT     = (unsigned short*)(ws + 30507008);   // 64 KB [256,128]

    hipLaunchKernelGGL(k_prep, dim3(448), dim3(256), 0, stream,
                       w_theta, w_phi, w_g, w_o, WT, woT);
    hipLaunchKernelGGL(k_proj, dim3(512), dim3(256), 0, stream,
                       x, WT, theta_b, phi_b, g_b);
    hipLaunchKernelGGL(k_pool, dim3(1536), dim3(256), 0, stream,
                       phi_b, g_b, phi_p, g_pT);
    hipLaunchKernelGGL(k_attn, dim3(1024), dim3(256), 0, stream,
                       theta_b, phi_p, g_pT, woT, x, b_o, sigma, out);
}